// Round 8
// baseline (605.210 us; speedup 1.0000x reference)
//
#include <hip/hip_runtime.h>
#include <stdint.h>

#define Nn 256
#define Mm 512
#define Dd 256

typedef unsigned short u16;
typedef unsigned int u32;
typedef __attribute__((ext_vector_type(8))) short bf16x8;
typedef __attribute__((ext_vector_type(4))) float f32x4;

__device__ __forceinline__ u16 f2b(float f) {
    unsigned u = __float_as_uint(f);
    return (u16)((u + 0x7FFFu + ((u >> 16) & 1u)) >> 16);  // RNE to bf16
}
__device__ __forceinline__ float b2f(u16 h) {
    return __uint_as_float(((unsigned)h) << 16);
}
__device__ __forceinline__ u32 pk2(float lo, float hi) {
    return (u32)f2b(lo) | ((u32)f2b(hi) << 16);
}
__device__ __forceinline__ void glds16(const u16* g, u16* l) {
    __builtin_amdgcn_global_load_lds((const __attribute__((address_space(1))) void*)g,
                                     (__attribute__((address_space(3))) void*)l, 16, 0, 0);
}

// ---------------------------------------------------------------------------
// Kernel 1a: partial column sums. grid = Nn*4; block (n, c) sums 128 rows.
// ---------------------------------------------------------------------------
__global__ __launch_bounds__(256) void mean_part_kernel(const float* __restrict__ x,
                                                        float* __restrict__ meanPart) {
    const int bid = blockIdx.x;
    const int n = bid >> 2, c = bid & 3;
    const int tid = threadIdx.x;
    const float* xb = x + (size_t)n * Mm * Dd + (size_t)c * 128 * Dd;
    float a0 = 0.f, a1 = 0.f, a2 = 0.f, a3 = 0.f;
    for (int m = 0; m < 128; m += 4) {
        a0 += xb[(m + 0) * Dd + tid];
        a1 += xb[(m + 1) * Dd + tid];
        a2 += xb[(m + 2) * Dd + tid];
        a3 += xb[(m + 3) * Dd + tid];
    }
    meanPart[((size_t)n * 4 + c) * Dd + tid] = a0 + a1 + a2 + a3;
}

// ---------------------------------------------------------------------------
// Kernel 1b: center + emit xn bf16 [n][m][d] and xnT bf16 [n][d][m].
// ---------------------------------------------------------------------------
__global__ __launch_bounds__(256) void center_tr_kernel(const float* __restrict__ x,
                                                        const float* __restrict__ meanPart,
                                                        u16* __restrict__ xn,
                                                        u16* __restrict__ xnT) {
    __shared__ float meanS[Dd];
    __shared__ u16 tileS[64 * 66];
    const int bid = blockIdx.x;
    const int n = bid >> 3, mt = bid & 7;
    const int tid = threadIdx.x;

    const float* mp = meanPart + (size_t)n * 4 * Dd;
    meanS[tid] = (mp[tid] + mp[Dd + tid] + mp[2 * Dd + tid] + mp[3 * Dd + tid]) * (1.0f / Mm);
    __syncthreads();

    const float* xb = x + (size_t)n * Mm * Dd;
    u16* xnb = xn + (size_t)n * Mm * Dd;
    u16* xtb = xnT + (size_t)n * Dd * Mm;
    const int mrow = tid >> 4, dq = tid & 15;
    const int tx2 = (tid & 31) * 2, ty = tid >> 5;

    for (int dt = 0; dt < Dd / 64; ++dt) {
        #pragma unroll
        for (int rr = 0; rr < 4; ++rr) {
            int ml = mrow + 16 * rr;
            int m = mt * 64 + ml;
            int d = dt * 64 + dq * 4;
            float4 v = *(const float4*)(xb + (size_t)m * Dd + d);
            float4 mu = *(const float4*)(meanS + d);
            u16 b0 = f2b(v.x - mu.x), b1 = f2b(v.y - mu.y);
            u16 b2 = f2b(v.z - mu.z), b3 = f2b(v.w - mu.w);
            u32 lo = (u32)b0 | ((u32)b1 << 16);
            u32 hi = (u32)b2 | ((u32)b3 << 16);
            *(uint2*)(xnb + (size_t)m * Dd + d) = make_uint2(lo, hi);
            tileS[(dq * 4 + 0) * 66 + ml] = b0;
            tileS[(dq * 4 + 1) * 66 + ml] = b1;
            tileS[(dq * 4 + 2) * 66 + ml] = b2;
            tileS[(dq * 4 + 3) * 66 + ml] = b3;
        }
        __syncthreads();
        #pragma unroll
        for (int r = 0; r < 8; ++r) {
            int dl = r * 8 + ty;
            u32 w = *(const u32*)(tileS + dl * 66 + tx2);
            *(u32*)(xtb + (size_t)(dt * 64 + dl) * Mm + mt * 64 + tx2) = w;
        }
        __syncthreads();
    }
}

// ---------------------------------------------------------------------------
// Kernel 2: sigma[n] = XnT @ XnT^T (raw fp32). XCD-swizzled.
// ---------------------------------------------------------------------------
__global__ __launch_bounds__(256) void sigma_kernel(const u16* __restrict__ xnT,
                                                    float* __restrict__ sigma) {
    __shared__ u16 sA[128 * 32];
    __shared__ u16 sB[128 * 32];
    const int bid = blockIdx.x;
    const int xcd = bid & 7, slot = bid >> 3;
    const int t = slot & 3;
    const int n = ((slot >> 2) << 3) | xcd;
    const int tr = t >> 1, tc = t & 1;
    const int tid = threadIdx.x;
    const int lane = tid & 63, wave = tid >> 6;
    const int wr = wave >> 1, wc = wave & 1;
    const int l15 = lane & 15, quad = lane >> 4;
    const int row0 = tid >> 2, q = tid & 3;
    const int wb8 = (tid & 192) * 8;

    const u16* base = xnT + (size_t)n * Dd * Mm;
    const u16* gA = base + (size_t)(tr * 128) * Mm;
    const u16* gB = base + (size_t)(tc * 128) * Mm;

    f32x4 acc[4][4];
    #pragma unroll
    for (int i = 0; i < 4; ++i)
        #pragma unroll
        for (int j = 0; j < 4; ++j) acc[i][j] = (f32x4){0.f, 0.f, 0.f, 0.f};

    for (int kk = 0; kk < Mm; kk += 32) {
        glds16(gA + (size_t)row0 * Mm + kk + q * 8, sA + wb8);
        glds16(gA + (size_t)(row0 + 64) * Mm + kk + q * 8, sA + 2048 + wb8);
        glds16(gB + (size_t)row0 * Mm + kk + q * 8, sB + wb8);
        glds16(gB + (size_t)(row0 + 64) * Mm + kk + q * 8, sB + 2048 + wb8);
        __syncthreads();
        bf16x8 a[4], b[4];
        #pragma unroll
        for (int i = 0; i < 4; ++i) a[i] = *(const bf16x8*)(sA + (wr * 64 + i * 16 + l15) * 32 + quad * 8);
        #pragma unroll
        for (int j = 0; j < 4; ++j) b[j] = *(const bf16x8*)(sB + (wc * 64 + j * 16 + l15) * 32 + quad * 8);
        #pragma unroll
        for (int i = 0; i < 4; ++i)
            #pragma unroll
            for (int j = 0; j < 4; ++j)
                acc[i][j] = __builtin_amdgcn_mfma_f32_16x16x32_bf16(a[i], b[j], acc[i][j], 0, 0, 0);
        __syncthreads();
    }

    float* sg = sigma + (size_t)n * Dd * Dd;
    #pragma unroll
    for (int i = 0; i < 4; ++i)
        #pragma unroll
        for (int j = 0; j < 4; ++j)
            #pragma unroll
            for (int r = 0; r < 4; ++r) {
                int row = tr * 128 + wr * 64 + i * 16 + quad * 4 + r;
                int col = tc * 128 + wc * 64 + j * 16 + l15;
                sg[row * Dd + col] = acc[i][j][r];
            }
}

// ---------------------------------------------------------------------------
// Fused NS chain v7: 512 threads / 8 waves per batch, 256 unified VGPRs.
// Dataflow bitwise-identical to v6; restructured to kill spill + cut LDS ops:
//   aF: wave's 32 P-rows cached in regs (16 ld128/iter), reused g1+g2.
//   g1: Q panel  (32x64 tiles, acc1 32 f32) -> sQ strip [64][256]
//   g2: P3 panel (32x64 tiles, acc2 32 f32) -> p3a[64] u32 (plain regs)
//   g3: P' = 1.5P - 0.5*P3@(Sh+Sl): 2 col passes x 8 k-steps, acc3 64 f32,
//       A dumped from p3a per step, S reg-prefetched distance 2.
// ---------------------------------------------------------------------------
__device__ __forceinline__ bf16x8 ldP(const u16* Plds, int row, int ch) {
    return *(const bf16x8*)(Plds + row * 256 + ((ch ^ (row & 7)) << 3));
}

__global__ __launch_bounds__(512, 2) void ns_chain_kernel(const float* __restrict__ sigma,
                                                          u16* __restrict__ Wg,
                                                          u16* __restrict__ Sh,
                                                          u16* __restrict__ Sl) {
    __shared__ __align__(16) u16 lds[81920];   // 160 KB
    u16* Plds = lds;
    u16* strips = lds + 65536;   // 16384 u16 = 32KB
    u16* sQ = strips;            // g1g2: [64][256]
    u16* sA = strips;            // g3: [256][32]
    u16* sS = strips + 8192;     // g3: Sh [128][32] + Sl [128][32]

    const int n = blockIdx.x, tid = threadIdx.x;
    const int lane = tid & 63, wave = tid >> 6;    // 8 waves
    const int l15 = lane & 15, quad = lane >> 4;

    const float* sg = sigma + (size_t)n * 65536;
    u16* shp = Sh + (size_t)n * 65536;
    u16* slp = Sl + (size_t)n * 65536;

    // ---- phase 0: trace, split S -> global, P1 -> LDS (swizzled) ----
    float* red = (float*)strips;
    if (tid < 256) red[tid] = sg[tid * 257];
    __syncthreads();
    for (int s = 128; s > 0; s >>= 1) {
        if (tid < s) red[tid] += red[tid + s];
        __syncthreads();
    }
    const float inv = 1.0f / red[0];
    const float rtr = sqrtf(511.0f * inv);

    #pragma unroll 4
    for (int itp = 0; itp < 32; ++itp) {
        int idx = itp * 2048 + tid * 4;
        float4 v = *(const float4*)(sg + idx);
        int row = idx >> 8, col = idx & 255;
        float s0 = v.x * inv, s1 = v.y * inv, s2 = v.z * inv, s3 = v.w * inv;
        u16 h0 = f2b(s0), h1 = f2b(s1), h2 = f2b(s2), h3 = f2b(s3);
        *(uint2*)(shp + idx) = make_uint2((u32)h0 | ((u32)h1 << 16), (u32)h2 | ((u32)h3 << 16));
        u16 e0 = f2b(s0 - b2f(h0)), e1 = f2b(s1 - b2f(h1));
        u16 e2 = f2b(s2 - b2f(h2)), e3 = f2b(s3 - b2f(h3));
        *(uint2*)(slp + idx) = make_uint2((u32)e0 | ((u32)e1 << 16), (u32)e2 | ((u32)e3 << 16));
        u16 p0 = f2b(((row == col + 0) ? 1.5f : 0.f) - 0.5f * s0);
        u16 p1 = f2b(((row == col + 1) ? 1.5f : 0.f) - 0.5f * s1);
        u16 p2 = f2b(((row == col + 2) ? 1.5f : 0.f) - 0.5f * s2);
        u16 p3 = f2b(((row == col + 3) ? 1.5f : 0.f) - 0.5f * s3);
        int pa = row * 256 + (((col >> 3) ^ (row & 7)) << 3) + (col & 7);
        *(uint2*)(Plds + pa) = make_uint2((u32)p0 | ((u32)p1 << 16), (u32)p2 | ((u32)p3 << 16));
    }
    __syncthreads();   // S stores visible before any re-read

    // S staging: waves 0-3 -> Sh, 4-7 -> Sl. Each lane stages 2x16B chunks.
    const u16* sBase = (wave < 4) ? shp : slp;
    const int w4 = wave & 3;
    const int cl_st = w4 * 32 + (lane >> 1);       // strip row (= S column)
    const int c0 = (lane & 1) * 2;                 // slot pair {c0, c0+1}
    const int kc0 = c0 ^ (cl_st & 3);              // pre-swizzled src chunks
    const int kc1 = (c0 + 1) ^ (cl_st & 3);
    u16* sDst = sS + ((wave < 4) ? 0 : 4096) + cl_st * 32 + c0 * 8;

    // ---- 3 NS iterations ----
    #pragma unroll 1
    for (int it = 0; it < 3; ++it) {
        const bool last = (it == 2);
        u32 p3a[64];

        // cache this wave's 32 P-rows as A fragments (reused g1+g2)
        bf16x8 aF[2][8];
        #pragma unroll
        for (int i16 = 0; i16 < 2; ++i16)
            #pragma unroll
            for (int s = 0; s < 8; ++s)
                aF[i16][s] = ldP(Plds, wave * 32 + i16 * 16 + l15, s * 4 + quad);

        // ---- g1+g2 fused per column panel jp ----
        #pragma unroll
        for (int jp = 0; jp < 4; ++jp) {
            {   // g1: Q[:, jp*64..+64], wave rows wave*32..+32
                f32x4 acc1[2][4];
                #pragma unroll
                for (int i16 = 0; i16 < 2; ++i16)
                    #pragma unroll
                    for (int jj = 0; jj < 4; ++jj) acc1[i16][jj] = (f32x4){0.f, 0.f, 0.f, 0.f};
                #pragma unroll
                for (int s = 0; s < 8; ++s) {
                    bf16x8 b[4];
                    #pragma unroll
                    for (int jj = 0; jj < 4; ++jj)
                        b[jj] = ldP(Plds, jp * 64 + jj * 16 + l15, s * 4 + quad);
                    #pragma unroll
                    for (int i16 = 0; i16 < 2; ++i16)
                        #pragma unroll
                        for (int jj = 0; jj < 4; ++jj)
                            acc1[i16][jj] = __builtin_amdgcn_mfma_f32_16x16x32_bf16(aF[i16][s], b[jj], acc1[i16][jj], 0, 0, 0);
                }
                #pragma unroll
                for (int i16 = 0; i16 < 2; ++i16)
                    #pragma unroll
                    for (int jj = 0; jj < 4; ++jj) {
                        int cl = jj * 16 + l15;
                        int k0 = wave * 32 + i16 * 16 + quad * 4;
                        int addr = cl * 256 + (((k0 >> 3) ^ (cl & 7)) << 3) + (k0 & 7);
                        *(uint2*)(sQ + addr) = make_uint2(pk2(acc1[i16][jj][0], acc1[i16][jj][1]),
                                                          pk2(acc1[i16][jj][2], acc1[i16][jj][3]));
                    }
            }
            __syncthreads();
            {   // g2: P3[:, jp*64..+64], wave rows wave*32..+32
                f32x4 acc2[2][4];
                #pragma unroll
                for (int i16 = 0; i16 < 2; ++i16)
                    #pragma unroll
                    for (int jj = 0; jj < 4; ++jj) acc2[i16][jj] = (f32x4){0.f, 0.f, 0.f, 0.f};
                #pragma unroll
                for (int s = 0; s < 8; ++s) {
                    bf16x8 b[4];
                    #pragma unroll
                    for (int jj = 0; jj < 4; ++jj) {
                        int cl = jj * 16 + l15;
                        b[jj] = *(const bf16x8*)(sQ + cl * 256 + (((s * 4 + quad) ^ (cl & 7)) << 3));
                    }
                    #pragma unroll
                    for (int i16 = 0; i16 < 2; ++i16)
                        #pragma unroll
                        for (int jj = 0; jj < 4; ++jj)
                            acc2[i16][jj] = __builtin_amdgcn_mfma_f32_16x16x32_bf16(aF[i16][s], b[jj], acc2[i16][jj], 0, 0, 0);
                }
                #pragma unroll
                for (int i16 = 0; i16 < 2; ++i16)
                    #pragma unroll
                    for (int jj = 0; jj < 4; ++jj)
                        #pragma unroll
                        for (int rh = 0; rh < 2; ++rh)
                            p3a[((jp * 4 + jj) * 2 + i16) * 2 + rh] =
                                pk2(acc2[i16][jj][2 * rh], acc2[i16][jj][2 * rh + 1]);
            }
            __syncthreads();
        }

        // ---- g3: P' = 1.5P - 0.5*P3@(Sh+Sl), 2 col passes x 8 k-steps ----
        uint4 gA0 = *(const uint4*)(sBase + (size_t)cl_st * 256 + kc0 * 8);            // t=0
        uint4 gA1 = *(const uint4*)(sBase + (size_t)cl_st * 256 + kc1 * 8);
        uint4 gB0 = *(const uint4*)(sBase + (size_t)cl_st * 256 + 32 + kc0 * 8);       // t=1
        uint4 gB1 = *(const uint4*)(sBase + (size_t)cl_st * 256 + 32 + kc1 * 8);
        #pragma unroll 1
        for (int jc = 0; jc < 2; ++jc) {
            f32x4 acc3[2][8];
            #pragma unroll
            for (int i16 = 0; i16 < 2; ++i16)
                #pragma unroll
                for (int j = 0; j < 8; ++j) acc3[i16][j] = (f32x4){0.f, 0.f, 0.f, 0.f};
            #pragma unroll
            for (int s = 0; s < 8; ++s) {
                // dump A-panel (k-slice s*32..+32 of P3) from p3a
                #pragma unroll
                for (int jjh = 0; jjh < 2; ++jjh) {
                    int jjsrc = (s & 1) * 2 + jjh;
                    int kloc = jjh * 16 + l15;
                    int ch = kloc >> 3, k7 = kloc & 7;
                    #pragma unroll
                    for (int i16 = 0; i16 < 2; ++i16)
                        #pragma unroll
                        for (int rh = 0; rh < 2; ++rh) {
                            u32 wv = p3a[(((s >> 1) * 4 + jjsrc) * 2 + i16) * 2 + rh];
                            #pragma unroll
                            for (int bit = 0; bit < 2; ++bit) {
                                int row = wave * 32 + i16 * 16 + quad * 4 + 2 * rh + bit;
                                int sw = (row ^ (row >> 2)) & 3;
                                sA[row * 32 + ((ch ^ sw) << 3) + k7] =
                                    (u16)(bit ? (wv >> 16) : (wv & 0xffffu));
                            }
                        }
                }
                // S panel for THIS step (loaded 2 steps ago) + prefetch t+2
                if ((s & 1) == 0) {
                    *(uint4*)sDst = gA0;
                    *(uint4*)(sDst + 8) = gA1;
                    int t2 = jc * 8 + s + 2;
                    if (t2 < 16) {
                        int jcn = t2 >> 3, sn = t2 & 7;
                        const u16* src = sBase + (size_t)(jcn * 128 + cl_st) * 256 + sn * 32;
                        gA0 = *(const uint4*)(src + kc0 * 8);
                        gA1 = *(const uint4*)(src + kc1 * 8);
                    }
                } else {
                    *(uint4*)sDst = gB0;
                    *(uint4*)(sDst + 8) = gB1;
                    int t2 = jc * 8 + s + 2;
                    if (t2 < 16) {
                        int jcn = t2 >> 3, sn = t2 & 7;
                        const u16* src = sBase + (size_t)(jcn * 128 + cl_st) * 256 + sn * 32;
                        gB0 = *(const uint4*)(src + kc0 * 8);
                        gB1 = *(const uint4*)(src + kc1 * 8);
                    }
                }
                asm volatile("s_waitcnt lgkmcnt(0)" ::: "memory");
                __builtin_amdgcn_s_barrier();
                // compute: 32x128 tile (rows wave*32.., cols jc*128..)
                {
                    bf16x8 a[2];
                    #pragma unroll
                    for (int i16 = 0; i16 < 2; ++i16) {
                        int ar = wave * 32 + i16 * 16 + l15;
                        int asw = (ar ^ (ar >> 2)) & 3;
                        a[i16] = *(const bf16x8*)(sA + ar * 32 + ((quad ^ asw) << 3));
                    }
                    #pragma unroll
                    for (int j = 0; j < 8; ++j) {
                        int cl = j * 16 + l15;
                        int co = cl * 32 + ((quad ^ (cl & 3)) << 3);
                        bf16x8 bh = *(const bf16x8*)(sS + co);
                        bf16x8 bl = *(const bf16x8*)(sS + 4096 + co);
                        #pragma unroll
                        for (int i16 = 0; i16 < 2; ++i16)
                            acc3[i16][j] = __builtin_amdgcn_mfma_f32_16x16x32_bf16(a[i16], bh, acc3[i16][j], 0, 0, 0);
                        #pragma unroll
                        for (int i16 = 0; i16 < 2; ++i16)
                            acc3[i16][j] = __builtin_amdgcn_mfma_f32_16x16x32_bf16(a[i16], bl, acc3[i16][j], 0, 0, 0);
                    }
                }
                asm volatile("s_waitcnt lgkmcnt(0)" ::: "memory");
                __builtin_amdgcn_s_barrier();
            }
            // epilogue for this column pass (own cells only -> race-free)
            #pragma unroll
            for (int i16 = 0; i16 < 2; ++i16)
                #pragma unroll
                for (int j = 0; j < 8; ++j)
                    #pragma unroll
                    for (int r = 0; r < 4; ++r) {
                        int row = wave * 32 + i16 * 16 + quad * 4 + r;
                        int col = jc * 128 + j * 16 + l15;
                        int pa = row * 256 + (((col >> 3) ^ (row & 7)) << 3) + (col & 7);
                        float pv = 1.5f * b2f(Plds[pa]) - 0.5f * acc3[i16][j][r];
                        Plds[pa] = f2b(last ? pv * rtr : pv);
                    }
        }
        __syncthreads();   // new P (or W) fully written before next phase
    }

    // ---- stream W = Plds out, coalesced uint4 ----
    u16* wg = Wg + (size_t)n * 65536;
    #pragma unroll
    for (int q = 0; q < 16; ++q) {
        int f = q * 512 + tid;        // 8192 chunks of 8 u16
        int row = f >> 5, ch = f & 31;
        uint4 v = *(const uint4*)(Plds + row * 256 + ((ch ^ (row & 7)) << 3));
        *(uint4*)(wg + row * 256 + ch * 8) = v;
    }
}

// ---------------------------------------------------------------------------
// Kernel 5: out = Xn @ W (W symmetric bf16, stride 65536). fp32 out.
// ---------------------------------------------------------------------------
__global__ __launch_bounds__(256) void final_gemm(const u16* __restrict__ xn,
                                                  const u16* __restrict__ Wh,
                                                  float* __restrict__ out) {
    __shared__ u16 sA[128 * 32];
    __shared__ u16 sB[128 * 32];
    const int bid = blockIdx.x;
    const int xcd = bid & 7, slot = bid >> 3;
    const int t = slot & 7;
    const int n = ((slot >> 3) << 3) | xcd;
    const int tr = t >> 1, tc = t & 1;
    const int tid = threadIdx.x;
    const int lane = tid & 63, wave = tid >> 6;
    const int wr = wave >> 1, wc = wave & 1;
    const int l15 = lane & 15, quad = lane >> 4;
    const int row0 = tid >> 2, q = tid & 3;
    const int wb8 = (tid & 192) * 8;

    const u16* gA = xn + (size_t)n * Mm * Dd + (size_t)(tr * 128) * Dd;
    const u16* gB = Wh + (size_t)n * Dd * Dd + (size_t)(tc * 128) * Dd;

    f32x4 acc[4][4];
    #pragma unroll
    for (int i = 0; i < 4; ++i)
        #pragma unroll
        for (int j = 0; j < 4; ++j) acc[i][j] = (f32x4){0.f, 0.f, 0.f, 0.f};

    for (int kk = 0; kk < Dd; kk += 32) {
        glds16(gA + (size_t)row0 * Dd + kk + q * 8, sA + wb8);
        glds16(gA + (size_t)(row0 + 64) * Dd + kk + q * 8, sA + 2048 + wb8);
        glds16(gB + (size_t)row0 * Dd + kk + q * 8, sB + wb8);
        glds16(gB + (size_t)(row0 + 64) * Dd + kk + q * 8, sB + 2048 + wb8);
        __syncthreads();
        bf16x8 a[4], b[4];
        #pragma unroll
        for (int i = 0; i < 4; ++i) a[i] = *(const bf16x8*)(sA + (wr * 64 + i * 16 + l15) * 32 + quad * 8);
        #pragma unroll
        for (int j = 0; j < 4; ++j) b[j] = *(const bf16x8*)(sB + (wc * 64 + j * 16 + l15) * 32 + quad * 8);
        #pragma unroll
        for (int i = 0; i < 4; ++i)
            #pragma unroll
            for (int j = 0; j < 4; ++j)
                acc[i][j] = __builtin_amdgcn_mfma_f32_16x16x32_bf16(a[i], b[j], acc[i][j], 0, 0, 0);
        __syncthreads();
    }

    float* ob = out + (size_t)n * Mm * Dd;
    #pragma unroll
    for (int i = 0; i < 4; ++i)
        #pragma unroll
        for (int j = 0; j < 4; ++j)
            #pragma unroll
            for (int r = 0; r < 4; ++r) {
                int row = tr * 128 + wr * 64 + i * 16 + quad * 4 + r;
                int col = tc * 128 + wc * 64 + j * 16 + l15;
                ob[(size_t)row * Dd + col] = acc[i][j][r];
            }
}

// ---------------------------------------------------------------------------
// Workspace (32MB units):
//  u0-1 xn | u2-3 xnT (dead after sigma) -> W at u2 (32MB)
//  u4-5 sigma fp32 | u6 Sh | u7 Sl | u9 meanPart
// ---------------------------------------------------------------------------
extern "C" void kernel_launch(void* const* d_in, const int* in_sizes, int n_in,
                              void* d_out, int out_size, void* d_ws, size_t ws_size,
                              hipStream_t stream) {
    const float* x = (const float*)d_in[0];
    float* out = (float*)d_out;
    char* ws = (char*)d_ws;
    const size_t MB32 = 33554432;

    u16* xn = (u16*)(ws + 0);
    u16* xnT = (u16*)(ws + 2 * MB32);
    u16* W = (u16*)(ws + 2 * MB32);    // alias xnT (dead after sigma)
    float* sigma = (float*)(ws + 4 * MB32);
    u16* Sh = (u16*)(ws + 6 * MB32);
    u16* Sl = (u16*)(ws + 7 * MB32);
    float* meanPart = (float*)(ws + 9 * MB32);

    mean_part_kernel<<<Nn * 4, 256, 0, stream>>>(x, meanPart);
    center_tr_kernel<<<Nn * 8, 256, 0, stream>>>(x, meanPart, xn, xnT);
    sigma_kernel<<<Nn * 4, 256, 0, stream>>>(xnT, sigma);
    ns_chain_kernel<<<Nn, 512, 0, stream>>>(sigma, W, Sh, Sl);
    final_gemm<<<Nn * 8, 256, 0, stream>>>(xn, W, out);
}